// Round 1
// baseline (265.679 us; speedup 1.0000x reference)
//
#include <hip/hip_runtime.h>
#include <math.h>

#define MAP 56
#define KST 10.0f
#define BATCH 16384
#define DIM 1024
#define HID 512

// ---------------------------------------------------------------------------
// Kernel 1: fold W1@W2 -> Weff [1024,3], and b1@W2 + b2 -> beff [3].
// Grid: 1025 blocks x 64 threads (block 1024 handles the bias row).
// ---------------------------------------------------------------------------
__global__ __launch_bounds__(64) void fold_weights(
    const float* __restrict__ W1, const float* __restrict__ b1,
    const float* __restrict__ W2, const float* __restrict__ b2,
    float* __restrict__ Weff, float* __restrict__ beff)
{
    const int d = blockIdx.x;        // 0..1023 = W1 row, 1024 = bias row
    const int lane = threadIdx.x;    // 0..63
    const float* row = (d < DIM) ? (W1 + (size_t)d * HID) : b1;

    float a0 = 0.f, a1 = 0.f, a2 = 0.f;
    for (int h = lane; h < HID; h += 64) {
        float w = row[h];
        const float* w2 = W2 + h * 3;
        a0 += w * w2[0];
        a1 += w * w2[1];
        a2 += w * w2[2];
    }
    #pragma unroll
    for (int off = 32; off; off >>= 1) {
        a0 += __shfl_down(a0, off, 64);
        a1 += __shfl_down(a1, off, 64);
        a2 += __shfl_down(a2, off, 64);
    }
    if (lane == 0) {
        if (d < DIM) {
            Weff[d * 3 + 0] = a0;
            Weff[d * 3 + 1] = a1;
            Weff[d * 3 + 2] = a2;
        } else {
            beff[0] = a0 + b2[0];
            beff[1] = a1 + b2[1];
            beff[2] = a2 + b2[2];
        }
    }
}

// ---------------------------------------------------------------------------
// Kernel 2: per batch row b:
//   t[0..2] = x[b,:] @ Weff + beff            (phase A)
//   Vx[i] = sig(k*(i-t0+h)) - sig(k*(i-t0-h)) (phase B, h = t2/2; Vy uses t1)
//   out[b,i,j] = Vx[i]*Vy[j]                  (phase C, float4 stores)
// Grid: 16384 blocks x 256 threads.
// ---------------------------------------------------------------------------
__global__ __launch_bounds__(256) void boxcar_kernel(
    const float* __restrict__ x, const float* __restrict__ Weff,
    const float* __restrict__ beff, float* __restrict__ out)
{
    __shared__ float sV[2][MAP];   // [0]=Vx, [1]=Vy
    __shared__ float sred[4][3];
    __shared__ float st[3];

    const int b = blockIdx.x;
    const int tid = threadIdx.x;

    // ---- Phase A: three 1024-length fp32 dot products ----
    const float4 xv = ((const float4*)(x + (size_t)b * DIM))[tid]; // 256*4 = 1024
    const float* wp = Weff + (tid * 4) * 3;   // 12 consecutive floats per thread
    float a0 = xv.x * wp[0] + xv.y * wp[3] + xv.z * wp[6] + xv.w * wp[9];
    float a1 = xv.x * wp[1] + xv.y * wp[4] + xv.z * wp[7] + xv.w * wp[10];
    float a2 = xv.x * wp[2] + xv.y * wp[5] + xv.z * wp[8] + xv.w * wp[11];
    #pragma unroll
    for (int off = 32; off; off >>= 1) {
        a0 += __shfl_down(a0, off, 64);
        a1 += __shfl_down(a1, off, 64);
        a2 += __shfl_down(a2, off, 64);
    }
    const int wave = tid >> 6;
    if ((tid & 63) == 0) {
        sred[wave][0] = a0; sred[wave][1] = a1; sred[wave][2] = a2;
    }
    __syncthreads();
    if (tid == 0) {
        st[0] = sred[0][0] + sred[1][0] + sred[2][0] + sred[3][0] + beff[0];
        st[1] = sred[0][1] + sred[1][1] + sred[2][1] + sred[3][1] + beff[1];
        st[2] = sred[0][2] + sred[1][2] + sred[2][2] + sred[3][2] + beff[2];
    }
    __syncthreads();
    const float t0 = st[0], t1 = st[1], t2 = st[2];

    // ---- Phase B: Vx (wave 0) and Vy (wave 1) ----
    if (tid < 128) {
        const int which = tid >> 6;        // 0 -> Vx(t0), 1 -> Vy(t1)
        const int i = tid & 63;
        if (i < MAP) {
            const float tc = which ? t1 : t0;
            const float u = (float)i - tc;
            const float hh = 0.5f * t2;
            const float p = 1.0f / (1.0f + __expf(-KST * (u + hh)));
            const float m = 1.0f / (1.0f + __expf(-KST * (u - hh)));
            sV[which][i] = p - m;
        }
    }
    __syncthreads();

    // ---- Phase C: outer product, 784 float4 stores ----
    float4* ob = (float4*)(out + (size_t)b * (MAP * MAP));
    for (int idx = tid; idx < (MAP * MAP / 4); idx += 256) {
        const int i = idx / (MAP / 4);          // row 0..55
        const int jq = idx - i * (MAP / 4);     // quad-col 0..13
        const float vx = sV[0][i];
        float4 o;
        o.x = vx * sV[1][4 * jq + 0];
        o.y = vx * sV[1][4 * jq + 1];
        o.z = vx * sV[1][4 * jq + 2];
        o.w = vx * sV[1][4 * jq + 3];
        ob[idx] = o;
    }
}

extern "C" void kernel_launch(void* const* d_in, const int* in_sizes, int n_in,
                              void* d_out, int out_size, void* d_ws, size_t ws_size,
                              hipStream_t stream) {
    const float* x  = (const float*)d_in[0];   // [16384, 1024]
    const float* W1 = (const float*)d_in[1];   // [1024, 512]
    const float* b1 = (const float*)d_in[2];   // [512]
    const float* W2 = (const float*)d_in[3];   // [512, 3]
    const float* b2 = (const float*)d_in[4];   // [3]
    float* out = (float*)d_out;                // [16384, 56, 56]

    float* Weff = (float*)d_ws;                // 3072 floats
    float* beff = Weff + DIM * 3;              // 3 floats

    fold_weights<<<DIM + 1, 64, 0, stream>>>(W1, b1, W2, b2, Weff, beff);
    boxcar_kernel<<<BATCH, 256, 0, stream>>>(x, Weff, beff, out);
}